// Round 4
// baseline (129.273 us; speedup 1.0000x reference)
//
#include <hip/hip_runtime.h>

#define BB 32
#define TT 1024
#define CCH 384
#define HH 64

typedef short short8 __attribute__((ext_vector_type(8)));
typedef float f32x4 __attribute__((ext_vector_type(4)));
typedef unsigned short ushort;

static __device__ __forceinline__ ushort f2bf(float f) {
    union { float f; unsigned u; } v; v.f = f;
    unsigned r = v.u + 0x7fff + ((v.u >> 16) & 1);
    return (ushort)(r >> 16);
}

// ---------------------------------------------------------------------------
// Kernel 1: swizzle the three f32 [384,64] weight matrices into MFMA
// B-fragment-contiguous bf16 layout. (unchanged, verified)
// ---------------------------------------------------------------------------
__global__ void wswz(const float* __restrict__ Wk, const float* __restrict__ Wq,
                     const float* __restrict__ Wv, ushort* __restrict__ wf) {
    const int mat = blockIdx.x, ks = blockIdx.y;
    const float* W = (mat == 0) ? Wk : ((mat == 1) ? Wq : Wv);
    const int t = threadIdx.x;
    const int ct = t >> 6, lane = t & 63, quad = lane >> 4, l15 = lane & 15;
    const int col = ct * 16 + l15;
    short8 d;
#pragma unroll
    for (int j = 0; j < 8; ++j)
        d[j] = (short)f2bf(W[(ks * 32 + quad * 8 + j) * 64 + col]);
    *(short8*)(wf + (((mat * 12 + ks) * 4 + ct) << 9) + lane * 8) = d;
}

// ---------------------------------------------------------------------------
// Kernel 2: fused QKV projection. (unchanged, verified)
// ---------------------------------------------------------------------------
#define XSTR 388
#define VS_STRIDE 68

__global__ __launch_bounds__(256, 2) void qkv(const float* __restrict__ x,
                                              const ushort* __restrict__ wf,
                                              ushort* __restrict__ kb,
                                              ushort* __restrict__ qb,
                                              ushort* __restrict__ vtb) {
    const int r0 = blockIdx.x * 64;
    const int tid = threadIdx.x;
    const int wv = tid >> 6, lane = tid & 63, l15 = lane & 15, quad = lane >> 4;

    __shared__ ushort xs[64 * XSTR];

#pragma unroll
    for (int kb3 = 0; kb3 < 3; ++kb3) {
        const int kbase = kb3 * 128;
        const int seg = (tid & 7) * 16;
#pragma unroll
        for (int i = 0; i < 2; ++i) {
            const int r = (tid >> 3) + 32 * i;
            const float* src = x + (size_t)(r0 + r) * CCH + kbase + seg;
            f32x4 v0 = *(const f32x4*)(src);
            f32x4 v1 = *(const f32x4*)(src + 4);
            f32x4 v2 = *(const f32x4*)(src + 8);
            f32x4 v3 = *(const f32x4*)(src + 12);
            short8 p0, p1;
#pragma unroll
            for (int j = 0; j < 4; ++j) {
                p0[j]     = (short)f2bf(v0[j]);
                p0[j + 4] = (short)f2bf(v1[j]);
                p1[j]     = (short)f2bf(v2[j]);
                p1[j + 4] = (short)f2bf(v3[j]);
            }
            *(short8*)(xs + r * XSTR + kbase + seg) = p0;
            *(short8*)(xs + r * XSTR + kbase + seg + 8) = p1;
        }
    }
    __syncthreads();

    f32x4 acc[12] = {};   // [mat*4+ct]
    short8 bf[2][12];
#pragma unroll
    for (int m = 0; m < 3; ++m)
#pragma unroll
        for (int ct = 0; ct < 4; ++ct)
            bf[0][m * 4 + ct] = *(const short8*)(wf + (((m * 12 + 0) * 4 + ct) << 9) + lane * 8);

#pragma unroll
    for (int ks = 0; ks < 12; ++ks) {
        short8 a = *(const short8*)(xs + (wv * 16 + l15) * XSTR + ks * 32 + quad * 8);
        if (ks < 11) {
#pragma unroll
            for (int m = 0; m < 3; ++m)
#pragma unroll
                for (int ct = 0; ct < 4; ++ct)
                    bf[(ks + 1) & 1][m * 4 + ct] =
                        *(const short8*)(wf + (((m * 12 + ks + 1) * 4 + ct) << 9) + lane * 8);
        }
#pragma unroll
        for (int f = 0; f < 12; ++f)
            acc[f] = __builtin_amdgcn_mfma_f32_16x16x32_bf16(a, bf[ks & 1][f], acc[f], 0, 0, 0);
    }

#pragma unroll
    for (int ct = 0; ct < 4; ++ct) {
#pragma unroll
        for (int r = 0; r < 4; ++r) {
            int row = r0 + wv * 16 + quad * 4 + r;
            int col = ct * 16 + l15;
            kb[row * 64 + col] = f2bf(acc[0 + ct][r]);
            qb[row * 64 + col] = f2bf(acc[4 + ct][r]);
        }
    }
    __syncthreads();
    ushort* vs = xs;
#pragma unroll
    for (int ct = 0; ct < 4; ++ct)
#pragma unroll
        for (int r = 0; r < 4; ++r)
            vs[(wv * 16 + quad * 4 + r) * VS_STRIDE + ct * 16 + l15] = f2bf(acc[8 + ct][r]);
    __syncthreads();
    {
        const int col = tid >> 2;
        const int rbase = (tid & 3) * 16;
        short8 d0, d1;
#pragma unroll
        for (int j = 0; j < 8; ++j) {
            d0[j] = (short)vs[(rbase + j) * VS_STRIDE + col];
            d1[j] = (short)vs[(rbase + 8 + j) * VS_STRIDE + col];
        }
        const int b = r0 >> 10;
        const int t = (r0 & 1023) + rbase;
        *(short8*)(vtb + b * 65536 + col * 1024 + t) = d0;
        *(short8*)(vtb + b * 65536 + col * 1024 + t + 8) = d1;
    }
}

// ---------------------------------------------------------------------------
// Kernel 3: fused causal attention — ONE barrier per key tile.
//   (r2 base, verified 122.2 us, + two structural edits)
//   EDIT A — Ks double-buffered: tile t+1's K is ds-written from prefetch
//     regs while tile t computes; the WAR barrier disappears. One
//     __syncthreads per tile (9/CU vs 18). Hazards: all waves are in the
//     same iteration (end-of-iter barrier); writes go to buf (it+1)&1 while
//     reads hit buf it&1; compiler drains lgkmcnt before s_barrier.
//   EDIT B — V fragments straight from global into registers (T14
//     issue-early/consume-late): issued at tile start, consumed by PV after
//     QK+softmax (~500 cy of cover). vtb/batch = 128 KB -> L1/L2 resident;
//     4 waves read identical addresses -> 3/4 hit L1. Removes Vs staging
//     (writes, barrier role, and 16 ds_read_b128/wave per tile).
//   Unlike round-1's failed version: K stays LDS-staged, 4-wave blocks,
//   k-prefetch pipeline intact. Complementary qt pairing kept (9 units/CU).
// ---------------------------------------------------------------------------
#define PSTR 136
#define KSTR 72

__global__ __launch_bounds__(256, 2) void attn(const ushort* __restrict__ qb,
                                               const ushort* __restrict__ kb,
                                               const ushort* __restrict__ vtb,
                                               float* __restrict__ out) {
    const int y = blockIdx.y;
    const int qt = (y < 8) ? (15 - y) : (y - 8);   // complementary CU pairing
    const int b = blockIdx.x;
    const int t0 = qt * 64;
    const int tid = threadIdx.x;
    const int wv = tid >> 6, lane = tid & 63, l15 = lane & 15, quad = lane >> 4;

    __shared__ ushort Ks[2][128 * KSTR]; // double-buffered K tiles [key][h]
    __shared__ ushort Ps[4 * 16 * PSTR]; // per-wave [q16][key128]
    ushort* Psw = Ps + wv * 16 * PSTR;

    const ushort* kbb = kb  + (size_t)b * 65536;
    const ushort* vbb = vtb + (size_t)b * 65536;

    const int qrow = b * 1024 + t0 + wv * 16 + l15;
    short8 qf0 = *(const short8*)(qb + qrow * 64 + quad * 8);
    short8 qf1 = *(const short8*)(qb + qrow * 64 + 32 + quad * 8);

    f32x4 o[4] = {};
    float li[4] = {0.f, 0.f, 0.f, 0.f};   // per-lane partial row sums
    const float c1 = 0.125f * 1.4426950408889634f;  // scale * log2(e)
    const float c2 = 10.0f * 1.4426950408889634f;   // fixed shift M=10

    const int nst = (qt >> 1) + 1;

    // prologue: K(0) -> Ks[0]; prefetch K(1) into regs
    short8 kr[4];
#pragma unroll
    for (int i = 0; i < 4; ++i) {
        int c = tid + i * 256;
        kr[i] = *(const short8*)(kbb + (c >> 3) * 64 + (c & 7) * 8);
    }
#pragma unroll
    for (int i = 0; i < 4; ++i) {
        int c = tid + i * 256;
        *(short8*)(Ks[0] + (c >> 3) * KSTR + (c & 7) * 8) = kr[i];
    }
    if (nst > 1) {
#pragma unroll
        for (int i = 0; i < 4; ++i) {
            int c = tid + i * 256;
            kr[i] = *(const short8*)(kbb + (128 + (c >> 3)) * 64 + (c & 7) * 8);
        }
    }
    __syncthreads();

    for (int it = 0; it < nst; ++it) {
        const int s0 = it * 128;
        const ushort* Kc = Ks[it & 1];

        // EDIT B: early V fragment loads for THIS tile (consumed by PV below)
        short8 vb[4][4];
#pragma unroll
        for (int ct = 0; ct < 4; ++ct)
#pragma unroll
            for (int kk = 0; kk < 4; ++kk)
                vb[ct][kk] = *(const short8*)(vbb + (ct * 16 + l15) * 1024 + s0 + kk * 32 + quad * 8);

        // EDIT A: stage NEXT K tile from regs into the other buffer;
        // then prefetch K(t+2) into regs
        if (it + 1 < nst) {
            ushort* Kn = Ks[(it + 1) & 1];
#pragma unroll
            for (int i = 0; i < 4; ++i) {
                int c = tid + i * 256;
                *(short8*)(Kn + (c >> 3) * KSTR + (c & 7) * 8) = kr[i];
            }
            if (it + 2 < nst) {
#pragma unroll
                for (int i = 0; i < 4; ++i) {
                    int c = tid + i * 256;
                    kr[i] = *(const short8*)(kbb + ((it + 2) * 128 + (c >> 3)) * 64 + (c & 7) * 8);
                }
            }
        }

        // S = Q K^T
        f32x4 s[8];
        __builtin_amdgcn_s_setprio(1);
#pragma unroll
        for (int ct = 0; ct < 8; ++ct) {
            f32x4 z = {};
            short8 b0 = *(const short8*)(Kc + (ct * 16 + l15) * KSTR + quad * 8);
            z = __builtin_amdgcn_mfma_f32_16x16x32_bf16(qf0, b0, z, 0, 0, 0);
            short8 b1 = *(const short8*)(Kc + (ct * 16 + l15) * KSTR + 32 + quad * 8);
            s[ct] = __builtin_amdgcn_mfma_f32_16x16x32_bf16(qf1, b1, z, 0, 0, 0);
        }
        __builtin_amdgcn_s_setprio(0);

        // fixed-shift softmax: p = exp2(s*c1 - c2); mask only on last tile
        if (it + 1 < nst) {
#pragma unroll
            for (int r = 0; r < 4; ++r) {
#pragma unroll
                for (int ct = 0; ct < 8; ++ct) {
                    float p = exp2f(s[ct][r] * c1 - c2);
                    li[r] += p;
                    Psw[(quad * 4 + r) * PSTR + ct * 16 + l15] = f2bf(p);
                }
            }
        } else {
#pragma unroll
            for (int r = 0; r < 4; ++r) {
                const int trow = t0 + wv * 16 + quad * 4 + r;
#pragma unroll
                for (int ct = 0; ct < 8; ++ct) {
                    int col = s0 + ct * 16 + l15;
                    float p = (col <= trow) ? exp2f(s[ct][r] * c1 - c2) : 0.f;
                    li[r] += p;
                    Psw[(quad * 4 + r) * PSTR + ct * 16 + l15] = f2bf(p);
                }
            }
        }

        // P: C-layout -> wave-local LDS -> A-layout (no barrier: same wave)
        short8 pa[4];
#pragma unroll
        for (int kk = 0; kk < 4; ++kk)
            pa[kk] = *(const short8*)(Psw + l15 * PSTR + kk * 32 + quad * 8);

        // O += P V — V from early-issued registers
        __builtin_amdgcn_s_setprio(1);
#pragma unroll
        for (int ct = 0; ct < 4; ++ct) {
#pragma unroll
            for (int kk = 0; kk < 4; ++kk)
                o[ct] = __builtin_amdgcn_mfma_f32_16x16x32_bf16(pa[kk], vb[ct][kk], o[ct], 0, 0, 0);
        }
        __builtin_amdgcn_s_setprio(0);

        __syncthreads();   // single per-tile barrier: Ks[(it+1)&1] now visible
    }

    // epilogue: reduce li across the 16 lanes of each row, normalize, store
#pragma unroll
    for (int r = 0; r < 4; ++r) {
        float rs = li[r];
#pragma unroll
        for (int off = 1; off < 16; off <<= 1)
            rs += __shfl_xor(rs, off);
        float inv = 1.0f / rs;
        int t = t0 + wv * 16 + quad * 4 + r;
#pragma unroll
        for (int ct = 0; ct < 4; ++ct) {
            int h = ct * 16 + l15;
            out[b * 65536 + t * 64 + h] = o[ct][r] * inv;
        }
    }
}

// ---------------------------------------------------------------------------
extern "C" void kernel_launch(void* const* d_in, const int* in_sizes, int n_in,
                              void* d_out, int out_size, void* d_ws, size_t ws_size,
                              hipStream_t stream) {
    const float* x  = (const float*)d_in[0];
    const float* Wk = (const float*)d_in[1];
    const float* Wq = (const float*)d_in[2];
    const float* Wv = (const float*)d_in[3];

    char* ws = (char*)d_ws;
    ushort* wf  = (ushort*)ws;                                   // 144 KiB swizzled weights
    ushort* kb  = (ushort*)(ws + 256 * 1024);                    // 4 MiB
    ushort* qb  = (ushort*)(ws + 256 * 1024 + 4u * 1024 * 1024); // 4 MiB
    ushort* vtb = (ushort*)(ws + 256 * 1024 + 8u * 1024 * 1024); // 4 MiB

    wswz<<<dim3(3, 12), dim3(256), 0, stream>>>(Wk, Wq, Wv, wf);
    qkv<<<dim3(512), dim3(256), 0, stream>>>(x, wf, kb, qb, vtb);
    attn<<<dim3(32, 16), dim3(256), 0, stream>>>(qb, kb, vtb, (float*)d_out);
}

// Round 5
// 121.877 us; speedup vs baseline: 1.0607x; 1.0607x over previous
//
#include <hip/hip_runtime.h>

#define BB 32
#define TT 1024
#define CCH 384
#define HH 64

typedef short short8 __attribute__((ext_vector_type(8)));
typedef float f32x4 __attribute__((ext_vector_type(4)));
typedef unsigned short ushort;

static __device__ __forceinline__ ushort f2bf(float f) {
    union { float f; unsigned u; } v; v.f = f;
    unsigned r = v.u + 0x7fff + ((v.u >> 16) & 1);
    return (ushort)(r >> 16);
}

// ---------------------------------------------------------------------------
// Kernel 1: swizzle the three f32 [384,64] weight matrices into MFMA
// B-fragment-contiguous bf16 layout. (unchanged, verified)
// ---------------------------------------------------------------------------
__global__ void wswz(const float* __restrict__ Wk, const float* __restrict__ Wq,
                     const float* __restrict__ Wv, ushort* __restrict__ wf) {
    const int mat = blockIdx.x, ks = blockIdx.y;
    const float* W = (mat == 0) ? Wk : ((mat == 1) ? Wq : Wv);
    const int t = threadIdx.x;
    const int ct = t >> 6, lane = t & 63, quad = lane >> 4, l15 = lane & 15;
    const int col = ct * 16 + l15;
    short8 d;
#pragma unroll
    for (int j = 0; j < 8; ++j)
        d[j] = (short)f2bf(W[(ks * 32 + quad * 8 + j) * 64 + col]);
    *(short8*)(wf + (((mat * 12 + ks) * 4 + ct) << 9) + lane * 8) = d;
}

// ---------------------------------------------------------------------------
// Kernel 2: fused QKV projection. (unchanged, verified)
// ---------------------------------------------------------------------------
#define XSTR 388
#define VS_STRIDE 68

__global__ __launch_bounds__(256, 2) void qkv(const float* __restrict__ x,
                                              const ushort* __restrict__ wf,
                                              ushort* __restrict__ kb,
                                              ushort* __restrict__ qb,
                                              ushort* __restrict__ vtb) {
    const int r0 = blockIdx.x * 64;
    const int tid = threadIdx.x;
    const int wv = tid >> 6, lane = tid & 63, l15 = lane & 15, quad = lane >> 4;

    __shared__ ushort xs[64 * XSTR];

#pragma unroll
    for (int kb3 = 0; kb3 < 3; ++kb3) {
        const int kbase = kb3 * 128;
        const int seg = (tid & 7) * 16;
#pragma unroll
        for (int i = 0; i < 2; ++i) {
            const int r = (tid >> 3) + 32 * i;
            const float* src = x + (size_t)(r0 + r) * CCH + kbase + seg;
            f32x4 v0 = *(const f32x4*)(src);
            f32x4 v1 = *(const f32x4*)(src + 4);
            f32x4 v2 = *(const f32x4*)(src + 8);
            f32x4 v3 = *(const f32x4*)(src + 12);
            short8 p0, p1;
#pragma unroll
            for (int j = 0; j < 4; ++j) {
                p0[j]     = (short)f2bf(v0[j]);
                p0[j + 4] = (short)f2bf(v1[j]);
                p1[j]     = (short)f2bf(v2[j]);
                p1[j + 4] = (short)f2bf(v3[j]);
            }
            *(short8*)(xs + r * XSTR + kbase + seg) = p0;
            *(short8*)(xs + r * XSTR + kbase + seg + 8) = p1;
        }
    }
    __syncthreads();

    f32x4 acc[12] = {};   // [mat*4+ct]
    short8 bf[2][12];
#pragma unroll
    for (int m = 0; m < 3; ++m)
#pragma unroll
        for (int ct = 0; ct < 4; ++ct)
            bf[0][m * 4 + ct] = *(const short8*)(wf + (((m * 12 + 0) * 4 + ct) << 9) + lane * 8);

#pragma unroll
    for (int ks = 0; ks < 12; ++ks) {
        short8 a = *(const short8*)(xs + (wv * 16 + l15) * XSTR + ks * 32 + quad * 8);
        if (ks < 11) {
#pragma unroll
            for (int m = 0; m < 3; ++m)
#pragma unroll
                for (int ct = 0; ct < 4; ++ct)
                    bf[(ks + 1) & 1][m * 4 + ct] =
                        *(const short8*)(wf + (((m * 12 + ks + 1) * 4 + ct) << 9) + lane * 8);
        }
#pragma unroll
        for (int f = 0; f < 12; ++f)
            acc[f] = __builtin_amdgcn_mfma_f32_16x16x32_bf16(a, bf[ks & 1][f], acc[f], 0, 0, 0);
    }

#pragma unroll
    for (int ct = 0; ct < 4; ++ct) {
#pragma unroll
        for (int r = 0; r < 4; ++r) {
            int row = r0 + wv * 16 + quad * 4 + r;
            int col = ct * 16 + l15;
            kb[row * 64 + col] = f2bf(acc[0 + ct][r]);
            qb[row * 64 + col] = f2bf(acc[4 + ct][r]);
        }
    }
    __syncthreads();
    ushort* vs = xs;
#pragma unroll
    for (int ct = 0; ct < 4; ++ct)
#pragma unroll
        for (int r = 0; r < 4; ++r)
            vs[(wv * 16 + quad * 4 + r) * VS_STRIDE + ct * 16 + l15] = f2bf(acc[8 + ct][r]);
    __syncthreads();
    {
        const int col = tid >> 2;
        const int rbase = (tid & 3) * 16;
        short8 d0, d1;
#pragma unroll
        for (int j = 0; j < 8; ++j) {
            d0[j] = (short)vs[(rbase + j) * VS_STRIDE + col];
            d1[j] = (short)vs[(rbase + 8 + j) * VS_STRIDE + col];
        }
        const int b = r0 >> 10;
        const int t = (r0 & 1023) + rbase;
        *(short8*)(vtb + b * 65536 + col * 1024 + t) = d0;
        *(short8*)(vtb + b * 65536 + col * 1024 + t + 8) = d1;
    }
}

// ---------------------------------------------------------------------------
// Kernel 3: fused causal attention — KEY-SPLIT waves.
//   r2 base (verified 122.2 us: LDS staging, 2 barriers/tile, complementary
//   qt pairing, fixed-shift softmax) with ONE structural change:
//   wave w owns ALL 64 q-rows x its 32-key slice [w*32, w*32+32) of each
//   128-key tile (was: 16 q-rows x all 128 keys). B-fragments (K and V) now
//   differ per wave and are REUSED across the wave's 4 q-subtiles:
//     QK B-frag reads: 4/wave (was 16);  PV: 4/wave (was 16).
//   LDS traffic/tile: 192 KB -> 96 KB (the 4x cross-wave read redundancy
//   was the modeled bottleneck: ~1500-2260 cy/tile at 85-128 B/cy).
//   MFMA count unchanged (32/wave/tile). Fixed-shift softmax => key-partial
//   (o, li) combine by pure addition in a once-per-block LDS epilogue.
//   r1/r4 lesson respected: K and V stay LDS-staged; prefetch + 2-barrier
//   pipeline byte-identical to r2.
// ---------------------------------------------------------------------------
#define PSTR2 40   // u16 stride of P rows: 2-way bank pattern on r/w (free)
#define KSTR 72
#define VSTR 136

__global__ __launch_bounds__(256, 2) void attn(const ushort* __restrict__ qb,
                                               const ushort* __restrict__ kb,
                                               const ushort* __restrict__ vtb,
                                               float* __restrict__ out) {
    const int y = blockIdx.y;
    const int qt = (y < 8) ? (15 - y) : (y - 8);   // complementary CU pairing
    const int b = blockIdx.x;
    const int t0 = qt * 64;
    const int tid = threadIdx.x;
    const int w = tid >> 6, lane = tid & 63, l15 = lane & 15, quad = lane >> 4;

    // LDS arena: main phase Ks(18432)+Vs(17408)+Ps(20480) = 56320 B
    //            epilogue  cmbO(12*1088*4=52224)+cmbL(1024) = 53248 B
    __shared__ __align__(16) char arena[56320];
    ushort* Ks = (ushort*)arena;                  // [key128][KSTR]
    ushort* Vs = (ushort*)(arena + 18432);        // [h64][VSTR]
    ushort* Ps = (ushort*)(arena + 35840);        // per-wave [q64][PSTR2]
    ushort* Psw = Ps + w * 64 * PSTR2;

    const ushort* kbb = kb  + (size_t)b * 65536;
    const ushort* vbb = vtb + (size_t)b * 65536;

    // Q A-fragments for all 4 q-subtiles (two 32-h halves each)
    short8 qf0[4], qf1[4];
#pragma unroll
    for (int m = 0; m < 4; ++m) {
        const int qrow = b * 1024 + t0 + m * 16 + l15;
        qf0[m] = *(const short8*)(qb + qrow * 64 + quad * 8);
        qf1[m] = *(const short8*)(qb + qrow * 64 + 32 + quad * 8);
    }

    f32x4 o[4][4] = {};      // [q-sub m][h-ct] partial over this wave's keys
    float li[4][4] = {};     // [m][r] per-lane partial row sums
    const float c1 = 0.125f * 1.4426950408889634f;  // scale * log2(e)
    const float c2 = 10.0f * 1.4426950408889634f;   // fixed shift M=10

    const int nst = (qt >> 1) + 1;

    // prologue + prefetch pipeline: byte-identical to r2
    short8 kr[4], vr[4];
#pragma unroll
    for (int i = 0; i < 4; ++i) {
        int c = tid + i * 256;
        kr[i] = *(const short8*)(kbb + (c >> 3) * 64 + (c & 7) * 8);
        vr[i] = *(const short8*)(vbb + (c >> 4) * 1024 + (c & 15) * 8);
    }

    for (int it = 0; it < nst; ++it) {
        const int s0 = it * 128;
        __syncthreads();   // WAR: previous iter's Ks/Vs reads complete
#pragma unroll
        for (int i = 0; i < 4; ++i) {
            int c = tid + i * 256;
            *(short8*)(Ks + (c >> 3) * KSTR + (c & 7) * 8) = kr[i];
            *(short8*)(Vs + (c >> 4) * VSTR + (c & 15) * 8) = vr[i];
        }
        __syncthreads();   // staging visible
        if (it + 1 < nst) {
            const int sn = s0 + 128;
#pragma unroll
            for (int i = 0; i < 4; ++i) {
                int c = tid + i * 256;
                kr[i] = *(const short8*)(kbb + (sn + (c >> 3)) * 64 + (c & 7) * 8);
                vr[i] = *(const short8*)(vbb + (c >> 4) * 1024 + sn + (c & 15) * 8);
            }
        }

        // S = Q K^T on this wave's 32-key slice; B-frags hoisted across m
        f32x4 s[4][2];
        __builtin_amdgcn_s_setprio(1);
#pragma unroll
        for (int g = 0; g < 2; ++g) {
            const ushort* kp = Ks + (w * 32 + g * 16 + l15) * KSTR + quad * 8;
            short8 b0 = *(const short8*)(kp);
            short8 b1 = *(const short8*)(kp + 32);
#pragma unroll
            for (int m = 0; m < 4; ++m) {
                f32x4 z = {};
                z = __builtin_amdgcn_mfma_f32_16x16x32_bf16(qf0[m], b0, z, 0, 0, 0);
                s[m][g] = __builtin_amdgcn_mfma_f32_16x16x32_bf16(qf1[m], b1, z, 0, 0, 0);
            }
        }
        __builtin_amdgcn_s_setprio(0);

        // fixed-shift softmax: p = exp2(s*c1 - c2); mask only on diag tile
        if (it + 1 < nst) {
#pragma unroll
            for (int m = 0; m < 4; ++m)
#pragma unroll
                for (int g = 0; g < 2; ++g)
#pragma unroll
                    for (int r = 0; r < 4; ++r) {
                        float p = exp2f(s[m][g][r] * c1 - c2);
                        li[m][r] += p;
                        Psw[(m * 16 + quad * 4 + r) * PSTR2 + g * 16 + l15] = f2bf(p);
                    }
        } else {
#pragma unroll
            for (int m = 0; m < 4; ++m)
#pragma unroll
                for (int g = 0; g < 2; ++g)
#pragma unroll
                    for (int r = 0; r < 4; ++r) {
                        const int trow = t0 + m * 16 + quad * 4 + r;
                        const int col = s0 + w * 32 + g * 16 + l15;
                        float p = (col <= trow) ? exp2f(s[m][g][r] * c1 - c2) : 0.f;
                        li[m][r] += p;
                        Psw[(m * 16 + quad * 4 + r) * PSTR2 + g * 16 + l15] = f2bf(p);
                    }
        }

        // P: C-layout -> wave-local LDS -> A-layout (no barrier: same wave)
        short8 pa[4];
#pragma unroll
        for (int m = 0; m < 4; ++m)
            pa[m] = *(const short8*)(Psw + (m * 16 + l15) * PSTR2 + quad * 8);

        // O += P V on this wave's key slice; V B-frags reused across m
        __builtin_amdgcn_s_setprio(1);
        short8 vbf[4];
#pragma unroll
        for (int ct = 0; ct < 4; ++ct)
            vbf[ct] = *(const short8*)(Vs + (ct * 16 + l15) * VSTR + w * 32 + quad * 8);
#pragma unroll
        for (int m = 0; m < 4; ++m)
#pragma unroll
            for (int ct = 0; ct < 4; ++ct)
                o[m][ct] = __builtin_amdgcn_mfma_f32_16x16x32_bf16(pa[m], vbf[ct], o[m][ct], 0, 0, 0);
        __builtin_amdgcn_s_setprio(0);
    }

    __syncthreads();   // all waves done with Ks/Vs/Ps before arena reuse

    // in-wave reduce li across the 16 l15 lanes (rows live in quad groups)
#pragma unroll
    for (int m = 0; m < 4; ++m)
#pragma unroll
        for (int r = 0; r < 4; ++r) {
            float rs = li[m][r];
#pragma unroll
            for (int off = 1; off < 16; off <<= 1)
                rs += __shfl_xor(rs, off);
            li[m][r] = rs;
        }

    // extract own q-subtile (m == w) into named regs (static indexing)
    f32x4 ow[4] = {};
    float lw[4] = {};
#pragma unroll
    for (int m = 0; m < 4; ++m)
        if (m == w) {
#pragma unroll
            for (int ct = 0; ct < 4; ++ct) ow[ct] = o[m][ct];
#pragma unroll
            for (int r = 0; r < 4; ++r) lw[r] = li[m][r];
        }

    // cross-wave combine: wave w publishes partials for m != w
    float* cmbO = (float*)arena;              // 12 slots x [ct4][row16][17]
    float* cmbL = (float*)(arena + 52224);    // [writer4][m4][row16]
#pragma unroll
    for (int m = 0; m < 4; ++m)
        if (m != w) {
            const int slot = w * 3 + m - (m > w ? 1 : 0);
            float* dst = cmbO + slot * 1088;
#pragma unroll
            for (int ct = 0; ct < 4; ++ct)
#pragma unroll
                for (int r = 0; r < 4; ++r)
                    dst[ct * 272 + (quad * 4 + r) * 17 + l15] = o[m][ct][r];
            if (l15 == 0)
#pragma unroll
                for (int r = 0; r < 4; ++r)
                    cmbL[(w * 4 + m) * 16 + quad * 4 + r] = li[m][r];
        }
    __syncthreads();
#pragma unroll
    for (int wp = 0; wp < 4; ++wp)
        if (wp != w) {
            const int slot = wp * 3 + w - (w > wp ? 1 : 0);
            const float* src = cmbO + slot * 1088;
#pragma unroll
            for (int ct = 0; ct < 4; ++ct)
#pragma unroll
                for (int r = 0; r < 4; ++r)
                    ow[ct][r] += src[ct * 272 + (quad * 4 + r) * 17 + l15];
#pragma unroll
            for (int r = 0; r < 4; ++r)
                lw[r] += cmbL[(wp * 4 + w) * 16 + quad * 4 + r];
        }

    // normalize + store own 16 q-rows
#pragma unroll
    for (int r = 0; r < 4; ++r) {
        float inv = 1.0f / lw[r];
        int t = t0 + w * 16 + quad * 4 + r;
#pragma unroll
        for (int ct = 0; ct < 4; ++ct)
            out[b * 65536 + t * 64 + ct * 16 + l15] = ow[ct][r] * inv;
    }
}

// ---------------------------------------------------------------------------
extern "C" void kernel_launch(void* const* d_in, const int* in_sizes, int n_in,
                              void* d_out, int out_size, void* d_ws, size_t ws_size,
                              hipStream_t stream) {
    const float* x  = (const float*)d_in[0];
    const float* Wk = (const float*)d_in[1];
    const float* Wq = (const float*)d_in[2];
    const float* Wv = (const float*)d_in[3];

    char* ws = (char*)d_ws;
    ushort* wf  = (ushort*)ws;                                   // 144 KiB swizzled weights
    ushort* kb  = (ushort*)(ws + 256 * 1024);                    // 4 MiB
    ushort* qb  = (ushort*)(ws + 256 * 1024 + 4u * 1024 * 1024); // 4 MiB
    ushort* vtb = (ushort*)(ws + 256 * 1024 + 8u * 1024 * 1024); // 4 MiB

    wswz<<<dim3(3, 12), dim3(256), 0, stream>>>(Wk, Wq, Wv, wf);
    qkv<<<dim3(512), dim3(256), 0, stream>>>(x, wf, kb, qb, vtb);
    attn<<<dim3(32, 16), dim3(256), 0, stream>>>(qb, kb, vtb, (float*)d_out);
}

// Round 6
// 121.032 us; speedup vs baseline: 1.0681x; 1.0070x over previous
//
#include <hip/hip_runtime.h>

#define BB 32
#define TT 1024
#define CCH 384
#define HH 64

typedef short short8 __attribute__((ext_vector_type(8)));
typedef float f32x4 __attribute__((ext_vector_type(4)));
typedef unsigned short ushort;

static __device__ __forceinline__ ushort f2bf(float f) {
    union { float f; unsigned u; } v; v.f = f;
    unsigned r = v.u + 0x7fff + ((v.u >> 16) & 1);
    return (ushort)(r >> 16);
}

// ---------------------------------------------------------------------------
// Kernel 1: swizzle the three f32 [384,64] weight matrices into MFMA
// B-fragment-contiguous bf16 layout. (unchanged, verified)
// ---------------------------------------------------------------------------
__global__ void wswz(const float* __restrict__ Wk, const float* __restrict__ Wq,
                     const float* __restrict__ Wv, ushort* __restrict__ wf) {
    const int mat = blockIdx.x, ks = blockIdx.y;
    const float* W = (mat == 0) ? Wk : ((mat == 1) ? Wq : Wv);
    const int t = threadIdx.x;
    const int ct = t >> 6, lane = t & 63, quad = lane >> 4, l15 = lane & 15;
    const int col = ct * 16 + l15;
    short8 d;
#pragma unroll
    for (int j = 0; j < 8; ++j)
        d[j] = (short)f2bf(W[(ks * 32 + quad * 8 + j) * 64 + col]);
    *(short8*)(wf + (((mat * 12 + ks) * 4 + ct) << 9) + lane * 8) = d;
}

// ---------------------------------------------------------------------------
// Kernel 2: fused QKV projection. (unchanged, verified)
// ---------------------------------------------------------------------------
#define XSTR 388
#define VS_STRIDE 68

__global__ __launch_bounds__(256, 2) void qkv(const float* __restrict__ x,
                                              const ushort* __restrict__ wf,
                                              ushort* __restrict__ kb,
                                              ushort* __restrict__ qb,
                                              ushort* __restrict__ vtb) {
    const int r0 = blockIdx.x * 64;
    const int tid = threadIdx.x;
    const int wv = tid >> 6, lane = tid & 63, l15 = lane & 15, quad = lane >> 4;

    __shared__ ushort xs[64 * XSTR];

#pragma unroll
    for (int kb3 = 0; kb3 < 3; ++kb3) {
        const int kbase = kb3 * 128;
        const int seg = (tid & 7) * 16;
#pragma unroll
        for (int i = 0; i < 2; ++i) {
            const int r = (tid >> 3) + 32 * i;
            const float* src = x + (size_t)(r0 + r) * CCH + kbase + seg;
            f32x4 v0 = *(const f32x4*)(src);
            f32x4 v1 = *(const f32x4*)(src + 4);
            f32x4 v2 = *(const f32x4*)(src + 8);
            f32x4 v3 = *(const f32x4*)(src + 12);
            short8 p0, p1;
#pragma unroll
            for (int j = 0; j < 4; ++j) {
                p0[j]     = (short)f2bf(v0[j]);
                p0[j + 4] = (short)f2bf(v1[j]);
                p1[j]     = (short)f2bf(v2[j]);
                p1[j + 4] = (short)f2bf(v3[j]);
            }
            *(short8*)(xs + r * XSTR + kbase + seg) = p0;
            *(short8*)(xs + r * XSTR + kbase + seg + 8) = p1;
        }
    }
    __syncthreads();

    f32x4 acc[12] = {};   // [mat*4+ct]
    short8 bf[2][12];
#pragma unroll
    for (int m = 0; m < 3; ++m)
#pragma unroll
        for (int ct = 0; ct < 4; ++ct)
            bf[0][m * 4 + ct] = *(const short8*)(wf + (((m * 12 + 0) * 4 + ct) << 9) + lane * 8);

#pragma unroll
    for (int ks = 0; ks < 12; ++ks) {
        short8 a = *(const short8*)(xs + (wv * 16 + l15) * XSTR + ks * 32 + quad * 8);
        if (ks < 11) {
#pragma unroll
            for (int m = 0; m < 3; ++m)
#pragma unroll
                for (int ct = 0; ct < 4; ++ct)
                    bf[(ks + 1) & 1][m * 4 + ct] =
                        *(const short8*)(wf + (((m * 12 + ks + 1) * 4 + ct) << 9) + lane * 8);
        }
#pragma unroll
        for (int f = 0; f < 12; ++f)
            acc[f] = __builtin_amdgcn_mfma_f32_16x16x32_bf16(a, bf[ks & 1][f], acc[f], 0, 0, 0);
    }

#pragma unroll
    for (int ct = 0; ct < 4; ++ct) {
#pragma unroll
        for (int r = 0; r < 4; ++r) {
            int row = r0 + wv * 16 + quad * 4 + r;
            int col = ct * 16 + l15;
            kb[row * 64 + col] = f2bf(acc[0 + ct][r]);
            qb[row * 64 + col] = f2bf(acc[4 + ct][r]);
        }
    }
    __syncthreads();
    ushort* vs = xs;
#pragma unroll
    for (int ct = 0; ct < 4; ++ct)
#pragma unroll
        for (int r = 0; r < 4; ++r)
            vs[(wv * 16 + quad * 4 + r) * VS_STRIDE + ct * 16 + l15] = f2bf(acc[8 + ct][r]);
    __syncthreads();
    {
        const int col = tid >> 2;
        const int rbase = (tid & 3) * 16;
        short8 d0, d1;
#pragma unroll
        for (int j = 0; j < 8; ++j) {
            d0[j] = (short)vs[(rbase + j) * VS_STRIDE + col];
            d1[j] = (short)vs[(rbase + 8 + j) * VS_STRIDE + col];
        }
        const int b = r0 >> 10;
        const int t = (r0 & 1023) + rbase;
        *(short8*)(vtb + b * 65536 + col * 1024 + t) = d0;
        *(short8*)(vtb + b * 65536 + col * 1024 + t + 8) = d1;
    }
}

// ---------------------------------------------------------------------------
// Kernel 3: fused causal attention — 32-ROW Q-TILES, 3 BLOCKS/CU.
//   r5 key-split structure (verified) with the q-tile halved: grid (32, 32),
//   each block owns 32 q-rows; wave w owns all 32 rows x its 32-key slice.
//   WHY (r4/r5 lesson): attn is bound by the SERIAL tile chain of the
//   heaviest block (8 iterations) running with ~1 resident block/CU for most
//   of its life — not by LDS BW (r5: halving reads was neutral) and not by
//   barrier count (r4). Halving the q-tile makes each of the 8 serial
//   iterations ~40% cheaper AND fits 3 blocks/CU (LDS 46080 B; VGPR capped
//   170 via __launch_bounds__(256,3)) so per-tile stalls hide behind other
//   blocks' waves.
//   Balance: qt map {31-y0, y0, 23-y0, y0+8} per CU -> exactly 18 half-units
//   on every CU, heavy-first dispatch (resident first: the 8/6/1-unit sets).
//   Epilogue: fixed-shift softmax => (o, li) partials combine by pure
//   addition across the 4 waves' key slices (r5-verified pattern, (w,m)
//   slots).
// ---------------------------------------------------------------------------
#define PSTR2 40   // u16 stride of P rows (80 B): 2-way bank pattern (free)
#define KSTR 72
#define VSTR 136

__global__ __launch_bounds__(256, 3) void attn(const ushort* __restrict__ qb,
                                               const ushort* __restrict__ kb,
                                               const ushort* __restrict__ vtb,
                                               float* __restrict__ out) {
    const int y = blockIdx.y;
    int qt;                                  // 32-row q-tile index, 0..31
    if (y < 8)       qt = 31 - y;            // 8,8,8,8,7,7,7,7 units
    else if (y < 16) qt = y - 8;             // 1,1,1,1,2,2,2,2
    else if (y < 24) qt = 39 - y;            // 6,6,6,6,5,5,5,5
    else             qt = y - 16;            // 3,3,3,3,4,4,4,4
    const int b = blockIdx.x;
    const int t0 = qt * 32;
    const int tid = threadIdx.x;
    const int w = tid >> 6, lane = tid & 63, l15 = lane & 15, quad = lane >> 4;

    // LDS arena: main Ks(18432)+Vs(17408)+Ps(10240) = 46080 B  (3 blocks/CU)
    //            epilogue slotO(34816)+slotL(512) = 35328 B
    __shared__ __align__(16) char arena[46080];
    ushort* Ks = (ushort*)arena;                  // [key128][KSTR]
    ushort* Vs = (ushort*)(arena + 18432);        // [h64][VSTR]
    ushort* Ps = (ushort*)(arena + 35840);        // per-wave [q32][PSTR2]
    ushort* Psw = Ps + w * 32 * PSTR2;

    const ushort* kbb = kb  + (size_t)b * 65536;
    const ushort* vbb = vtb + (size_t)b * 65536;

    // Q A-fragments for the 2 q-subtiles (two 32-h halves each)
    short8 qf0[2], qf1[2];
#pragma unroll
    for (int m = 0; m < 2; ++m) {
        const int qrow = b * 1024 + t0 + m * 16 + l15;
        qf0[m] = *(const short8*)(qb + qrow * 64 + quad * 8);
        qf1[m] = *(const short8*)(qb + qrow * 64 + 32 + quad * 8);
    }

    f32x4 o[2][4] = {};      // [q-sub m][h-ct] partial over this wave's keys
    float li[2][4] = {};     // [m][r] per-lane partial row sums
    const float c1 = 0.125f * 1.4426950408889634f;  // scale * log2(e)
    const float c2 = 10.0f * 1.4426950408889634f;   // fixed shift M=10

    const int nst = (qt >> 2) + 1;           // number of 128-key tiles

    // prologue + prefetch pipeline (r2/r5-verified form)
    short8 kr[4], vr[4];
#pragma unroll
    for (int i = 0; i < 4; ++i) {
        int c = tid + i * 256;
        kr[i] = *(const short8*)(kbb + (c >> 3) * 64 + (c & 7) * 8);
        vr[i] = *(const short8*)(vbb + (c >> 4) * 1024 + (c & 15) * 8);
    }

    for (int it = 0; it < nst; ++it) {
        const int s0 = it * 128;
        __syncthreads();   // WAR: previous iter's Ks/Vs reads complete
#pragma unroll
        for (int i = 0; i < 4; ++i) {
            int c = tid + i * 256;
            *(short8*)(Ks + (c >> 3) * KSTR + (c & 7) * 8) = kr[i];
            *(short8*)(Vs + (c >> 4) * VSTR + (c & 15) * 8) = vr[i];
        }
        __syncthreads();   // staging visible
        if (it + 1 < nst) {
            const int sn = s0 + 128;
#pragma unroll
            for (int i = 0; i < 4; ++i) {
                int c = tid + i * 256;
                kr[i] = *(const short8*)(kbb + (sn + (c >> 3)) * 64 + (c & 7) * 8);
                vr[i] = *(const short8*)(vbb + (c >> 4) * 1024 + sn + (c & 15) * 8);
            }
        }

        // S = Q K^T on this wave's 32-key slice; B-frags reused across m
        f32x4 s[2][2];
        __builtin_amdgcn_s_setprio(1);
#pragma unroll
        for (int g = 0; g < 2; ++g) {
            const ushort* kp = Ks + (w * 32 + g * 16 + l15) * KSTR + quad * 8;
            short8 b0 = *(const short8*)(kp);
            short8 b1 = *(const short8*)(kp + 32);
#pragma unroll
            for (int m = 0; m < 2; ++m) {
                f32x4 z = {};
                z = __builtin_amdgcn_mfma_f32_16x16x32_bf16(qf0[m], b0, z, 0, 0, 0);
                s[m][g] = __builtin_amdgcn_mfma_f32_16x16x32_bf16(qf1[m], b1, z, 0, 0, 0);
            }
        }
        __builtin_amdgcn_s_setprio(0);

        // fixed-shift softmax: p = exp2(s*c1 - c2); mask only on diag tile
        if (it + 1 < nst) {
#pragma unroll
            for (int m = 0; m < 2; ++m)
#pragma unroll
                for (int g = 0; g < 2; ++g)
#pragma unroll
                    for (int r = 0; r < 4; ++r) {
                        float p = exp2f(s[m][g][r] * c1 - c2);
                        li[m][r] += p;
                        Psw[(m * 16 + quad * 4 + r) * PSTR2 + g * 16 + l15] = f2bf(p);
                    }
        } else {
#pragma unroll
            for (int m = 0; m < 2; ++m)
#pragma unroll
                for (int g = 0; g < 2; ++g)
#pragma unroll
                    for (int r = 0; r < 4; ++r) {
                        const int trow = t0 + m * 16 + quad * 4 + r;
                        const int col = s0 + w * 32 + g * 16 + l15;
                        float p = (col <= trow) ? exp2f(s[m][g][r] * c1 - c2) : 0.f;
                        li[m][r] += p;
                        Psw[(m * 16 + quad * 4 + r) * PSTR2 + g * 16 + l15] = f2bf(p);
                    }
        }

        // P: C-layout -> wave-local LDS -> A-layout (no barrier: same wave)
        short8 pa[2];
#pragma unroll
        for (int m = 0; m < 2; ++m)
            pa[m] = *(const short8*)(Psw + (m * 16 + l15) * PSTR2 + quad * 8);

        // O += P V on this wave's key slice; V B-frags reused across m
        __builtin_amdgcn_s_setprio(1);
        short8 vbf[4];
#pragma unroll
        for (int ct = 0; ct < 4; ++ct)
            vbf[ct] = *(const short8*)(Vs + (ct * 16 + l15) * VSTR + w * 32 + quad * 8);
#pragma unroll
        for (int m = 0; m < 2; ++m)
#pragma unroll
            for (int ct = 0; ct < 4; ++ct)
                o[m][ct] = __builtin_amdgcn_mfma_f32_16x16x32_bf16(pa[m], vbf[ct], o[m][ct], 0, 0, 0);
        __builtin_amdgcn_s_setprio(0);
    }

    __syncthreads();   // all waves done with Ks/Vs/Ps before arena reuse

    // in-wave reduce li across the 16 l15 lanes (full row sums)
#pragma unroll
    for (int m = 0; m < 2; ++m)
#pragma unroll
        for (int r = 0; r < 4; ++r) {
            float rs = li[m][r];
#pragma unroll
            for (int off = 1; off < 16; off <<= 1)
                rs += __shfl_xor(rs, off);
            li[m][r] = rs;
        }

    // publish all (w, m) partials; combine by addition (fixed-shift softmax)
    float* slotO = (float*)arena;              // [8][4][16][17] f32
    float* slotL = (float*)(arena + 34816);    // [8][16] f32
#pragma unroll
    for (int m = 0; m < 2; ++m) {
        const int sl = w * 2 + m;
#pragma unroll
        for (int ct = 0; ct < 4; ++ct)
#pragma unroll
            for (int r = 0; r < 4; ++r)
                slotO[(sl * 4 + ct) * 272 + (quad * 4 + r) * 17 + l15] = o[m][ct][r];
        if (l15 == 0)
#pragma unroll
            for (int r = 0; r < 4; ++r)
                slotL[sl * 16 + quad * 4 + r] = li[m][r];
    }
    __syncthreads();

    // wave w finalizes subtile mh = w>>1, column pair cb = (w&1)*2
    {
        const int mh = w >> 1, cb = (w & 1) * 2;
#pragma unroll
        for (int r = 0; r < 4; ++r) {
            float lsum = 0.f;
#pragma unroll
            for (int wp = 0; wp < 4; ++wp)
                lsum += slotL[(wp * 2 + mh) * 16 + quad * 4 + r];
            const float inv = 1.0f / lsum;
            const int t = t0 + mh * 16 + quad * 4 + r;
#pragma unroll
            for (int cc = 0; cc < 2; ++cc) {
                const int ct = cb + cc;
                float v = 0.f;
#pragma unroll
                for (int wp = 0; wp < 4; ++wp)
                    v += slotO[((wp * 2 + mh) * 4 + ct) * 272 + (quad * 4 + r) * 17 + l15];
                out[b * 65536 + t * 64 + ct * 16 + l15] = v * inv;
            }
        }
    }
}

// ---------------------------------------------------------------------------
extern "C" void kernel_launch(void* const* d_in, const int* in_sizes, int n_in,
                              void* d_out, int out_size, void* d_ws, size_t ws_size,
                              hipStream_t stream) {
    const float* x  = (const float*)d_in[0];
    const float* Wk = (const float*)d_in[1];
    const float* Wq = (const float*)d_in[2];
    const float* Wv = (const float*)d_in[3];

    char* ws = (char*)d_ws;
    ushort* wf  = (ushort*)ws;                                   // 144 KiB swizzled weights
    ushort* kb  = (ushort*)(ws + 256 * 1024);                    // 4 MiB
    ushort* qb  = (ushort*)(ws + 256 * 1024 + 4u * 1024 * 1024); // 4 MiB
    ushort* vtb = (ushort*)(ws + 256 * 1024 + 8u * 1024 * 1024); // 4 MiB

    wswz<<<dim3(3, 12), dim3(256), 0, stream>>>(Wk, Wq, Wv, wf);
    qkv<<<dim3(512), dim3(256), 0, stream>>>(x, wf, kb, qb, vtb);
    attn<<<dim3(32, 32), dim3(256), 0, stream>>>(qb, kb, vtb, (float*)d_out);
}